// Round 9
// baseline (618.354 us; speedup 1.0000x reference)
//
#include <hip/hip_runtime.h>
#include <math.h>

constexpr int MM = 10000;   // N_NODES
constexpr int DD = 256;     // D_IN == D_OUT
constexpr int EE = 320000;  // N_EDGES

// ---------------------------------------------------------------------------
// K1: GEMM H = X @ W^T (fp32), 64x64 tile, BK=16, 256 thr, 4x4 micro-tile.
// (unchanged from the r5 passing kernel)
// ---------------------------------------------------------------------------
__global__ __launch_bounds__(256) void gemm_h(const float* __restrict__ X,
                                              const float* __restrict__ W,
                                              float* __restrict__ H) {
    __shared__ float xs[16][68];
    __shared__ float ws[16][68];
    const int tid = threadIdx.x;
    const int bm = (blockIdx.x % 157) << 6;
    const int bn = (blockIdx.x / 157) << 6;
    const int lr = tid >> 2;          // 0..63
    const int lc = (tid & 3) << 2;    // 0,4,8,12
    const int tx = tid & 15;
    const int ty = tid >> 4;

    float acc[4][4] = {};

    for (int k0 = 0; k0 < DD; k0 += 16) {
        const int gr = bm + lr;
        float4 xv = make_float4(0.f, 0.f, 0.f, 0.f);
        if (gr < MM) xv = *(const float4*)(X + (size_t)gr * DD + k0 + lc);
        float4 wv = *(const float4*)(W + (size_t)(bn + lr) * DD + k0 + lc);
        xs[lc + 0][lr] = xv.x; xs[lc + 1][lr] = xv.y;
        xs[lc + 2][lr] = xv.z; xs[lc + 3][lr] = xv.w;
        ws[lc + 0][lr] = wv.x; ws[lc + 1][lr] = wv.y;
        ws[lc + 2][lr] = wv.z; ws[lc + 3][lr] = wv.w;
        __syncthreads();
#pragma unroll
        for (int k = 0; k < 16; ++k) {
            float4 xr4 = *(const float4*)(&xs[k][ty << 2]);
            float4 wr4 = *(const float4*)(&ws[k][tx << 2]);
            float xr[4] = {xr4.x, xr4.y, xr4.z, xr4.w};
            float wr[4] = {wr4.x, wr4.y, wr4.z, wr4.w};
#pragma unroll
            for (int i = 0; i < 4; ++i)
#pragma unroll
                for (int j = 0; j < 4; ++j) acc[i][j] += xr[i] * wr[j];
        }
        __syncthreads();
    }
#pragma unroll
    for (int i = 0; i < 4; ++i) {
        const int r = bm + (ty << 2) + i;
        if (r < MM) {
            *(float4*)(H + (size_t)r * DD + bn + (tx << 2)) =
                make_float4(acc[i][0], acc[i][1], acc[i][2], acc[i][3]);
        }
    }
}

// ---------------------------------------------------------------------------
// K2: per-node dots (wave per node) + BOTH degree counts (dst and src).
// 2500 blocks * 256 thr; edge part: 640k threads cover EE (<=1 edge each).
// ---------------------------------------------------------------------------
__global__ __launch_bounds__(256) void dots_deg(const float* __restrict__ h,
                                                const float* __restrict__ att_src,
                                                const float* __restrict__ att_dst,
                                                const int* __restrict__ src,
                                                const int* __restrict__ dst,
                                                float* __restrict__ s_ss,
                                                float* __restrict__ s_sd,
                                                int* __restrict__ deg_d,
                                                int* __restrict__ deg_s) {
    const int wv = threadIdx.x >> 6, lane = threadIdx.x & 63;
    const int node = blockIdx.x * 4 + wv;
    if (node < MM) {
        float4 a = ((const float4*)att_src)[lane];
        float4 b = ((const float4*)att_dst)[lane];
        float4 v = ((const float4*)h)[(size_t)node * 64 + lane];
        float ds = v.x * a.x + v.y * a.y + v.z * a.z + v.w * a.w;
        float dd = v.x * b.x + v.y * b.y + v.z * b.z + v.w * b.w;
#pragma unroll
        for (int off = 32; off; off >>= 1) {
            ds += __shfl_xor(ds, off);
            dd += __shfl_xor(dd, off);
        }
        if (lane == 0) { s_ss[node] = ds; s_sd[node] = dd; }
    }
    const int e = blockIdx.x * 256 + threadIdx.x;
    if (e < EE) {
        atomicAdd(&deg_d[dst[e]], 1);
        atomicAdd(&deg_s[src[e]], 1);
    }
}

// ---------------------------------------------------------------------------
// K3: dual exclusive scan (deg_d -> ro_d/cur_d, deg_s -> ro_s/cur_s).
// 1 block, 256 thr, C=40.
// ---------------------------------------------------------------------------
__global__ __launch_bounds__(256) void scan2(const int* __restrict__ deg_d,
                                             const int* __restrict__ deg_s,
                                             int* __restrict__ ro_d,
                                             int* __restrict__ cur_d,
                                             int* __restrict__ ro_s,
                                             int* __restrict__ cur_s) {
    constexpr int C = 40;  // 256*40 >= MM
    __shared__ int wsum[4];
    const int t = threadIdx.x, wv = t >> 6, lane = t & 63;
    const int i0 = t * C;
#pragma unroll
    for (int which = 0; which < 2; ++which) {
        const int* dg = which ? deg_s : deg_d;
        int* ro  = which ? ro_s : ro_d;
        int* cur = which ? cur_s : cur_d;
        int total = 0;
#pragma unroll 8
        for (int k = 0; k < C; ++k) { int i = i0 + k; total += (i < MM) ? dg[i] : 0; }
        int incl = total;
#pragma unroll
        for (int off = 1; off < 64; off <<= 1) {
            int u = __shfl_up(incl, off);
            if (lane >= off) incl += u;
        }
        if (lane == 63) wsum[wv] = incl;
        __syncthreads();
        if (t == 0) {
            int run = 0;
#pragma unroll
            for (int w2 = 0; w2 < 4; ++w2) { int v = wsum[w2]; wsum[w2] = run; run += v; }
        }
        __syncthreads();
        int run = wsum[wv] + incl - total;   // global exclusive prefix
#pragma unroll 8
        for (int k = 0; k < C; ++k) {
            const int i = i0 + k;
            if (i < MM) {
                const int v = dg[i];
                cur[i] = run;
                run += v;
                ro[i + 1] = run;
            }
        }
        if (t == 0) ro[0] = 0;
        __syncthreads();   // protect wsum reuse
    }
}

// ---------------------------------------------------------------------------
// K4: per-edge score + scatter into BOTH CSRs. 1250*256 == EE exactly.
// ---------------------------------------------------------------------------
__global__ __launch_bounds__(256) void score_scat(const int* __restrict__ src,
                                                  const int* __restrict__ dst,
                                                  const float* __restrict__ s_ss,
                                                  const float* __restrict__ s_sd,
                                                  float* __restrict__ score,
                                                  int* __restrict__ cur_d,
                                                  int* __restrict__ csr_d,
                                                  int* __restrict__ cur_s,
                                                  int* __restrict__ csr_s) {
    const int e = blockIdx.x * 256 + threadIdx.x;
    const int s = src[e], d = dst[e];
    float sc = s_ss[s] + s_sd[d];
    sc = (sc >= 0.f) ? sc : 0.2f * sc;
    score[e] = sc;
    csr_d[atomicAdd(&cur_d[d], 1)] = e;
    csr_s[atomicAdd(&cur_s[s], 1)] = e;
}

// ---------------------------------------------------------------------------
// K5: per-dst softmax stats (m, 1/sum) -> msum[node]. Wave per node.
// ---------------------------------------------------------------------------
__global__ __launch_bounds__(256) void stats(const float* __restrict__ score,
                                             const int* __restrict__ csr_d,
                                             const int* __restrict__ ro_d,
                                             float2* __restrict__ msum) {
    const int wv = threadIdx.x >> 6, lane = threadIdx.x & 63;
    const int node = blockIdx.x * 4 + wv;
    if (node >= MM) return;
    const int r0 = ro_d[node], r1 = ro_d[node + 1];
    if (r0 == r1) return;

    // max (cache first 4 chunks of scores in registers)
    float s_reg[4];
    float m = -INFINITY;
#pragma unroll
    for (int c = 0; c < 4; ++c) {
        const int i = r0 + c * 64 + lane;
        const float s = (i < r1) ? score[csr_d[i]] : -INFINITY;
        s_reg[c] = s;
        m = fmaxf(m, s);
    }
    for (int i = r0 + 256 + lane; i < r1; i += 64) m = fmaxf(m, score[csr_d[i]]);
#pragma unroll
    for (int off = 32; off; off >>= 1) m = fmaxf(m, __shfl_xor(m, off));

    // exp-sum
    float sum = 0.f;
#pragma unroll
    for (int c = 0; c < 4; ++c) {
        const int i = r0 + c * 64 + lane;
        if (i < r1) sum += expf(s_reg[c] - m);
    }
    for (int i = r0 + 256 + lane; i < r1; i += 64) sum += expf(score[csr_d[i]] - m);
#pragma unroll
    for (int off = 32; off; off >>= 1) sum += __shfl_xor(sum, off);

    if (lane == 0) msum[node] = make_float2(m, 1.f / sum);
}

// ---------------------------------------------------------------------------
// K6: finale — role-split blocks, no inter-role dependency:
//  even b: att row-writer (wave per src-row: zeros + alpha fixups = the
//          ONLY pass over the 400 MB matrix; replaces the standalone fill)
//  odd  b: out-features aggregation (wave per dst-node; alpha recomputed
//          from msum — no max/sum passes)
// ---------------------------------------------------------------------------
__global__ __launch_bounds__(256) void finale(const float* __restrict__ h,
                                              const float* __restrict__ score,
                                              const int* __restrict__ src,
                                              const int* __restrict__ dst,
                                              const int* __restrict__ csr_d,
                                              const int* __restrict__ ro_d,
                                              const int* __restrict__ csr_s,
                                              const int* __restrict__ ro_s,
                                              const float2* __restrict__ msum,
                                              float* __restrict__ out,
                                              float* __restrict__ att) {
    const int wv = threadIdx.x >> 6, lane = threadIdx.x & 63;
    const int b = blockIdx.x;

    if ((b & 1) == 0) {
        // ---- row-writer: row = src node ----
        const int row = (b >> 1) * 4 + wv;
        if (row >= MM) return;
        float4* rowp = (float4*)(att + (size_t)row * MM);  // 2500 float4
        for (int i = lane; i < 2500; i += 64)
            rowp[i] = make_float4(0.f, 0.f, 0.f, 0.f);
        __syncthreads();  // drain zero-stores (s_waitcnt vmcnt(0) before barrier)
        const int r0 = ro_s[row], r1 = ro_s[row + 1];
        for (int i = r0 + lane; i < r1; i += 64) {
            const int e = csr_s[i];
            const int d = dst[e];
            const float2 ms = msum[d];
            att[(size_t)row * MM + d] = expf(score[e] - ms.x) * ms.y;
        }
    } else {
        // ---- aggregation: node = dst node ----
        const int node = (b >> 1) * 4 + wv;
        if (node >= MM) return;
        const int r0 = ro_d[node], r1 = ro_d[node + 1];
        const float4* h4 = (const float4*)h;
        float4* out4 = (float4*)out;
        if (r0 == r1) {  // no incoming edges: keep own transformed features
            out4[(size_t)node * 64 + lane] = h4[(size_t)node * 64 + lane];
            return;
        }
        const float2 ms = msum[node];
        float4 acc = make_float4(0.f, 0.f, 0.f, 0.f);
        for (int base = r0; base < r1; base += 64) {
            const int i = base + lane;
            float a = 0.f; int sn = 0;
            if (i < r1) {
                const int e = csr_d[i];
                a = expf(score[e] - ms.x) * ms.y;
                sn = src[e];
            }
            const int cnt = min(64, r1 - base);
            for (int j = 0; j < cnt; ++j) {
                const float aj = __shfl(a, j);
                const int sj = __shfl(sn, j);
                const float4 hv = h4[(size_t)sj * 64 + lane];
                acc.x += aj * hv.x; acc.y += aj * hv.y;
                acc.z += aj * hv.z; acc.w += aj * hv.w;
            }
        }
        out4[(size_t)node * 64 + lane] = acc;
    }
}

// ---------------------------------------------------------------------------
extern "C" void kernel_launch(void* const* d_in, const int* in_sizes, int n_in,
                              void* d_out, int out_size, void* d_ws, size_t ws_size,
                              hipStream_t stream) {
    const float* x       = (const float*)d_in[0];
    const float* W       = (const float*)d_in[1];
    const float* att_src = (const float*)d_in[2];
    const float* att_dst = (const float*)d_in[3];
    const int*   eidx    = (const int*)d_in[4];
    const int* src = eidx;
    const int* dst = eidx + EE;

    float* out_feat = (float*)d_out;               // [10000,256]
    float* att      = out_feat + (size_t)MM * DD;  // [10000,10000]

    // workspace layout
    float*  h     = (float*)d_ws;                   // MM*DD
    float*  s_ss  = h + (size_t)MM * DD;            // MM
    float*  s_sd  = s_ss + MM;                      // MM
    float*  score = s_sd + MM;                      // EE
    float2* msum  = (float2*)(score + EE);          // MM float2
    int*    deg_d = (int*)(msum + MM);              // MM   \ zeroed by one
    int*    deg_s = deg_d + MM;                     // MM   / memset (2*MM)
    int*    ro_d  = deg_s + MM;                     // MM+1
    int*    ro_s  = ro_d + MM + 1;                  // MM+1
    int*    cur_d = ro_s + MM + 1;                  // MM
    int*    cur_s = cur_d + MM;                     // MM
    int*    csr_d = cur_s + MM;                     // EE
    int*    csr_s = csr_d + EE;                     // EE

    hipMemsetAsync(deg_d, 0, 2 * MM * sizeof(int), stream);

    gemm_h<<<628, 256, 0, stream>>>(x, W, h);
    dots_deg<<<2500, 256, 0, stream>>>(h, att_src, att_dst, src, dst,
                                       s_ss, s_sd, deg_d, deg_s);
    scan2<<<1, 256, 0, stream>>>(deg_d, deg_s, ro_d, cur_d, ro_s, cur_s);
    score_scat<<<1250, 256, 0, stream>>>(src, dst, s_ss, s_sd, score,
                                         cur_d, csr_d, cur_s, csr_s);
    stats<<<2500, 256, 0, stream>>>(score, csr_d, ro_d, msum);
    finale<<<5000, 256, 0, stream>>>(h, score, src, dst, csr_d, ro_d,
                                     csr_s, ro_s, msum, out_feat, att);
}

// Round 10
// 542.002 us; speedup vs baseline: 1.1409x; 1.1409x over previous
//
#include <hip/hip_runtime.h>
#include <math.h>

constexpr int MM = 10000;   // N_NODES
constexpr int DD = 256;     // D_IN == D_OUT
constexpr int EE = 320000;  // N_EDGES

// attention-matrix zero-fill partition (float4 units; total = MM*MM/4 = 25e6)
constexpr size_t ZT = (size_t)MM * MM / 4;   // 25,000,000
constexpr size_t Z1 = 11250000;              // gemm slice         (180 MB)
constexpr size_t Z2 = 16250000;              // dots slice          (80 MB)
                                             // scoreScatter: [Z2,ZT) (140 MB)

__device__ __forceinline__ void zero_att_slice(float4* att4, size_t lo, size_t hi) {
    const size_t stride = (size_t)gridDim.x * blockDim.x;
    for (size_t p = lo + (size_t)blockIdx.x * blockDim.x + threadIdx.x; p < hi; p += stride)
        att4[p] = make_float4(0.f, 0.f, 0.f, 0.f);
}

// ---------------------------------------------------------------------------
// Dispatch 1 (630 blocks): blocks 0..627 GEMM H = X @ W^T (64x64 tile, BK=16,
// 4x4 micro-tile); blocks 628..629 zero deg[]. All blocks stream-zero 180 MB
// of the attention matrix first.
// ---------------------------------------------------------------------------
__global__ __launch_bounds__(256) void gemm_h(const float* __restrict__ X,
                                              const float* __restrict__ W,
                                              float* __restrict__ H,
                                              float4* __restrict__ att4,
                                              int* __restrict__ deg) {
    zero_att_slice(att4, 0, Z1);

    const int bid = blockIdx.x;
    if (bid >= 628) {  // deg-zero blocks (replaces the hipMemsetAsync dispatch)
        const int half = bid - 628;  // 0 or 1
        for (int i = half * 5000 + threadIdx.x; i < (half + 1) * 5000; i += 256)
            deg[i] = 0;
        return;
    }

    __shared__ float xs[16][68];
    __shared__ float ws[16][68];
    const int tid = threadIdx.x;
    const int bm = (bid % 157) << 6;
    const int bn = (bid / 157) << 6;
    const int lr = tid >> 2;          // 0..63
    const int lc = (tid & 3) << 2;    // 0,4,8,12
    const int tx = tid & 15;
    const int ty = tid >> 4;

    float acc[4][4] = {};

    for (int k0 = 0; k0 < DD; k0 += 16) {
        const int gr = bm + lr;
        float4 xv = make_float4(0.f, 0.f, 0.f, 0.f);
        if (gr < MM) xv = *(const float4*)(X + (size_t)gr * DD + k0 + lc);
        float4 wv = *(const float4*)(W + (size_t)(bn + lr) * DD + k0 + lc);
        xs[lc + 0][lr] = xv.x; xs[lc + 1][lr] = xv.y;
        xs[lc + 2][lr] = xv.z; xs[lc + 3][lr] = xv.w;
        ws[lc + 0][lr] = wv.x; ws[lc + 1][lr] = wv.y;
        ws[lc + 2][lr] = wv.z; ws[lc + 3][lr] = wv.w;
        __syncthreads();
#pragma unroll
        for (int k = 0; k < 16; ++k) {
            float4 xr4 = *(const float4*)(&xs[k][ty << 2]);
            float4 wr4 = *(const float4*)(&ws[k][tx << 2]);
            float xr[4] = {xr4.x, xr4.y, xr4.z, xr4.w};
            float wr[4] = {wr4.x, wr4.y, wr4.z, wr4.w};
#pragma unroll
            for (int i = 0; i < 4; ++i)
#pragma unroll
                for (int j = 0; j < 4; ++j) acc[i][j] += xr[i] * wr[j];
        }
        __syncthreads();
    }
#pragma unroll
    for (int i = 0; i < 4; ++i) {
        const int r = bm + (ty << 2) + i;
        if (r < MM) {
            *(float4*)(H + (size_t)r * DD + bn + (tx << 2)) =
                make_float4(acc[i][0], acc[i][1], acc[i][2], acc[i][3]);
        }
    }
}

// ---------------------------------------------------------------------------
// Dispatch 2 (2500 blocks): per-node dots (wave per node) + degree counting
// + 80 MB fill slice.
// ---------------------------------------------------------------------------
__global__ __launch_bounds__(256) void node_dots_deg(const float* __restrict__ h,
                                                     const float* __restrict__ att_src,
                                                     const float* __restrict__ att_dst,
                                                     const int* __restrict__ dst,
                                                     float* __restrict__ s_src,
                                                     float* __restrict__ s_dst,
                                                     int* __restrict__ deg,
                                                     float4* __restrict__ att4) {
    zero_att_slice(att4, Z1, Z2);

    const int wv = threadIdx.x >> 6, lane = threadIdx.x & 63;
    const int node = blockIdx.x * 4 + wv;
    if (node < MM) {
        float4 a = ((const float4*)att_src)[lane];
        float4 b = ((const float4*)att_dst)[lane];
        float4 v = ((const float4*)h)[(size_t)node * 64 + lane];
        float ds = v.x * a.x + v.y * a.y + v.z * a.z + v.w * a.w;
        float dd = v.x * b.x + v.y * b.y + v.z * b.z + v.w * b.w;
#pragma unroll
        for (int off = 32; off; off >>= 1) {
            ds += __shfl_xor(ds, off);
            dd += __shfl_xor(dd, off);
        }
        if (lane == 0) { s_src[node] = ds; s_dst[node] = dd; }
    }
    // degree counting (edge-indexed grid-stride; 2500*256 = 640k >= EE)
    const int gt = blockIdx.x * 256 + threadIdx.x;
    for (int e = gt; e < EE; e += gridDim.x * 256) atomicAdd(&deg[dst[e]], 1);
}

// ---------------------------------------------------------------------------
// Dispatch 3: exclusive scan of deg -> row_off[MM+1], cursor. 1 block, 1024 thr.
// ---------------------------------------------------------------------------
__global__ __launch_bounds__(1024) void scan_deg(const int* __restrict__ deg,
                                                 int* __restrict__ row_off,
                                                 int* __restrict__ cursor) {
    constexpr int C = 10;  // 1024*10 >= MM
    __shared__ int wsum[16];
    const int t = threadIdx.x, wv = t >> 6, lane = t & 63;
    const int i0 = t * C;
    int total = 0;
#pragma unroll
    for (int k = 0; k < C; ++k) {
        const int i = i0 + k;
        total += (i < MM) ? deg[i] : 0;
    }
    int incl = total;
#pragma unroll
    for (int off = 1; off < 64; off <<= 1) {
        int u = __shfl_up(incl, off);
        if (lane >= off) incl += u;
    }
    if (lane == 63) wsum[wv] = incl;
    __syncthreads();
    if (t < 16) {
        int v = wsum[t];
#pragma unroll
        for (int off = 1; off < 16; off <<= 1) {
            int u = __shfl_up(v, off);
            if (t >= off) v += u;
        }
        wsum[t] = v;
    }
    __syncthreads();
    const int wave_excl = (wv == 0) ? 0 : wsum[wv - 1];
    int run = wave_excl + incl - total;  // global exclusive prefix
#pragma unroll
    for (int k = 0; k < C; ++k) {
        const int i = i0 + k;
        if (i < MM) {
            const int v = deg[i];
            cursor[i] = run;
            run += v;
            row_off[i + 1] = run;
        }
    }
    if (t == 0) row_off[0] = 0;
}

// ---------------------------------------------------------------------------
// Dispatch 4 (1250 blocks): per-edge score + CSR scatter + 140 MB fill slice.
// 1250*256 == EE exactly.
// ---------------------------------------------------------------------------
__global__ __launch_bounds__(256) void score_scatter(const int* __restrict__ src,
                                                     const int* __restrict__ dst,
                                                     const float* __restrict__ s_src,
                                                     const float* __restrict__ s_dst,
                                                     float* __restrict__ score,
                                                     int* __restrict__ cursor,
                                                     int* __restrict__ csr,
                                                     float4* __restrict__ att4) {
    zero_att_slice(att4, Z2, ZT);
    const int e = blockIdx.x * 256 + threadIdx.x;
    const int s = src[e], d = dst[e];
    float sc = s_src[s] + s_dst[d];
    sc = (sc >= 0.f) ? sc : 0.2f * sc;
    score[e] = sc;
    const int pos = atomicAdd(&cursor[d], 1);
    csr[pos] = e;
}

// ---------------------------------------------------------------------------
// Dispatch 5 (2500 blocks): wave-per-node softmax + attention scatter +
// aggregation. Phase-3 gather loop has 2-way ILP (two edges in flight).
// ---------------------------------------------------------------------------
__global__ __launch_bounds__(256) void node_agg(const float* __restrict__ h,
                                                const float* __restrict__ score,
                                                const int* __restrict__ src,
                                                const int* __restrict__ csr,
                                                const int* __restrict__ row_off,
                                                float* __restrict__ out,
                                                float* __restrict__ att) {
    const int wv = threadIdx.x >> 6, lane = threadIdx.x & 63;
    const int node = blockIdx.x * 4 + wv;
    if (node >= MM) return;
    const int r0 = row_off[node], r1 = row_off[node + 1];
    const float4* h4 = (const float4*)h;
    float4* out4 = (float4*)out;

    if (r0 == r1) {  // no incoming edges: keep own transformed features
        out4[(size_t)node * 64 + lane] = h4[(size_t)node * 64 + lane];
        return;
    }

    // phase 1: max (cache first 4 chunks in registers)
    int e_reg[4];
    float s_reg[4];
    float m = -INFINITY;
#pragma unroll
    for (int c = 0; c < 4; ++c) {
        const int i = r0 + c * 64 + lane;
        const bool vld = i < r1;
        const int e = vld ? csr[i] : 0;
        const float s = vld ? score[e] : -INFINITY;
        e_reg[c] = e; s_reg[c] = s;
        m = fmaxf(m, s);
    }
    for (int i = r0 + 256 + lane; i < r1; i += 64) m = fmaxf(m, score[csr[i]]);
#pragma unroll
    for (int off = 32; off; off >>= 1) m = fmaxf(m, __shfl_xor(m, off));

    // phase 2: exp + sum (s_reg becomes ex)
    float sum = 0.f;
#pragma unroll
    for (int c = 0; c < 4; ++c) {
        const int i = r0 + c * 64 + lane;
        const float ex = (i < r1) ? expf(s_reg[c] - m) : 0.f;
        s_reg[c] = ex;
        sum += ex;
    }
    for (int i = r0 + 256 + lane; i < r1; i += 64) sum += expf(score[csr[i]] - m);
#pragma unroll
    for (int off = 32; off; off >>= 1) sum += __shfl_xor(sum, off);
    const float inv = 1.f / sum;

    // phase 3: alpha scatter + shfl-broadcast aggregation, 2-way ILP
    float4 acc = make_float4(0.f, 0.f, 0.f, 0.f);
#pragma unroll
    for (int c = 0; c < 4; ++c) {
        const int base = r0 + c * 64;
        if (base < r1) {
            const int i = base + lane;
            float a = 0.f; int sn = 0;
            if (i < r1) {
                a = s_reg[c] * inv;
                sn = src[e_reg[c]];
                att[(size_t)sn * MM + node] = a;
            }
            const int cnt = min(64, r1 - base);
            int j = 0;
            for (; j + 1 < cnt; j += 2) {   // two edges in flight
                const float aj0 = __shfl(a, j);
                const int   sj0 = __shfl(sn, j);
                const float aj1 = __shfl(a, j + 1);
                const int   sj1 = __shfl(sn, j + 1);
                const float4 hv0 = h4[(size_t)sj0 * 64 + lane];
                const float4 hv1 = h4[(size_t)sj1 * 64 + lane];
                acc.x += aj0 * hv0.x; acc.y += aj0 * hv0.y;
                acc.z += aj0 * hv0.z; acc.w += aj0 * hv0.w;
                acc.x += aj1 * hv1.x; acc.y += aj1 * hv1.y;
                acc.z += aj1 * hv1.z; acc.w += aj1 * hv1.w;
            }
            if (j < cnt) {
                const float aj = __shfl(a, j);
                const int   sj = __shfl(sn, j);
                const float4 hv = h4[(size_t)sj * 64 + lane];
                acc.x += aj * hv.x; acc.y += aj * hv.y;
                acc.z += aj * hv.z; acc.w += aj * hv.w;
            }
        }
    }
    for (int base = r0 + 256; base < r1; base += 64) {  // overflow (deg>256)
        const int i = base + lane;
        float a = 0.f; int sn = 0;
        if (i < r1) {
            const int e = csr[i];
            a = expf(score[e] - m) * inv;
            sn = src[e];
            att[(size_t)sn * MM + node] = a;
        }
        const int cnt = min(64, r1 - base);
        int j = 0;
        for (; j + 1 < cnt; j += 2) {
            const float aj0 = __shfl(a, j);
            const int   sj0 = __shfl(sn, j);
            const float aj1 = __shfl(a, j + 1);
            const int   sj1 = __shfl(sn, j + 1);
            const float4 hv0 = h4[(size_t)sj0 * 64 + lane];
            const float4 hv1 = h4[(size_t)sj1 * 64 + lane];
            acc.x += aj0 * hv0.x; acc.y += aj0 * hv0.y;
            acc.z += aj0 * hv0.z; acc.w += aj0 * hv0.w;
            acc.x += aj1 * hv1.x; acc.y += aj1 * hv1.y;
            acc.z += aj1 * hv1.z; acc.w += aj1 * hv1.w;
        }
        if (j < cnt) {
            const float aj = __shfl(a, j);
            const int   sj = __shfl(sn, j);
            const float4 hv = h4[(size_t)sj * 64 + lane];
            acc.x += aj * hv.x; acc.y += aj * hv.y;
            acc.z += aj * hv.z; acc.w += aj * hv.w;
        }
    }
    out4[(size_t)node * 64 + lane] = acc;
}

// ---------------------------------------------------------------------------
extern "C" void kernel_launch(void* const* d_in, const int* in_sizes, int n_in,
                              void* d_out, int out_size, void* d_ws, size_t ws_size,
                              hipStream_t stream) {
    const float* x       = (const float*)d_in[0];
    const float* W       = (const float*)d_in[1];
    const float* att_src = (const float*)d_in[2];
    const float* att_dst = (const float*)d_in[3];
    const int*   eidx    = (const int*)d_in[4];
    const int* src = eidx;
    const int* dst = eidx + EE;

    float* out_feat = (float*)d_out;               // [10000,256]
    float* att      = out_feat + (size_t)MM * DD;  // [10000,10000]
    float4* att4    = (float4*)att;

    float* h       = (float*)d_ws;                  // MM*DD
    float* s_src   = h + (size_t)MM * DD;           // MM
    float* s_dst   = s_src + MM;                    // MM
    float* score   = s_dst + MM;                    // EE
    int*   deg     = (int*)(score + EE);            // MM
    int*   row_off = deg + MM;                      // MM+1
    int*   cursor  = row_off + MM + 1;              // MM
    int*   csr     = cursor + MM;                   // EE

    gemm_h<<<630, 256, 0, stream>>>(x, W, h, att4, deg);
    node_dots_deg<<<2500, 256, 0, stream>>>(h, att_src, att_dst, dst,
                                            s_src, s_dst, deg, att4);
    scan_deg<<<1, 1024, 0, stream>>>(deg, row_off, cursor);
    score_scatter<<<1250, 256, 0, stream>>>(src, dst, s_src, s_dst,
                                            score, cursor, csr, att4);
    node_agg<<<2500, 256, 0, stream>>>(h, score, src, csr, row_off, out_feat, att);
}